// Round 2
// baseline (82.355 us; speedup 1.0000x reference)
//
#include <hip/hip_runtime.h>
#include <math.h>

#define NTX_EPS 1e-8f

// Kernel 1: one block per (batch, chunk-slot). 256 threads.
// slot 0..3 -> level0 (D=4096) d-chunk slot*1024
// slot 4..5 -> level1 (D=2048) d-chunk (slot-4)*1024
// slot 6    -> level2 (D=1024) full (computes its loss directly)
// Each block computes partial G[n][m] = sum_d ts[b,n,d]*M[b,m,d] over its
// 1024-float d-range, M = [ts;rs]. m<16: t-t, m>=16: t-r. Partial rs norms too.
// Partials (528 floats) written to ws slot (b*6+slot) for slots 0..5.
__global__ __launch_bounds__(256)
void ntxent_partial(const float* __restrict__ ts0, const float* __restrict__ rs0,
                    const float* __restrict__ ts1, const float* __restrict__ rs1,
                    const float* __restrict__ ts2, const float* __restrict__ rs2,
                    float* __restrict__ ws, float* __restrict__ out)
{
    __shared__ float M[32][132];
    __shared__ float Gp[4][16][36];   // per-wave partial Gram
    __shared__ float rn2[16];
    __shared__ float tnormS[16], rnormS[16];

    const int bid  = blockIdx.x;
    const int b    = bid / 7;
    const int slot = bid % 7;

    const float* tp; const float* rp; int D; int chunk;
    if (slot < 4)      { tp = ts0; rp = rs0; D = 4096; chunk = slot; }
    else if (slot < 6) { tp = ts1; rp = rs1; D = 2048; chunk = slot - 4; }
    else               { tp = ts2; rp = rs2; D = 1024; chunk = 0; }

    const int t    = threadIdx.x;
    const int half = t >> 7;           // 0: ts rows, 1: rs rows
    const int lrow = (t >> 3) & 15;
    const int lc4  = t & 7;
    const float* gsrc = (half ? rp : tp) + (size_t)b * 16 * D + (size_t)lrow * D
                        + (size_t)chunk * 1024;

    const int tile = t & 7;
    const int s    = t >> 3;           // d-slice 0..31
    const int ti   = tile >> 2;
    const int tj   = tile & 3;

    float acc[8][8];
#pragma unroll
    for (int i = 0; i < 8; ++i)
#pragma unroll
        for (int j = 0; j < 8; ++j) acc[i][j] = 0.f;

    float rsq = 0.f;

    // prefetch inner-chunk 0
    float4 stg[4];
#pragma unroll
    for (int it = 0; it < 4; ++it)
        stg[it] = *(const float4*)(gsrc + (lc4 + 8*it) * 4);

    const float* Arow = &M[ti*8][0] + 4*s;
    const float* Brow = &M[tj*8][0] + 4*s;

    for (int c = 0; c < 8; ++c) {          // 8 inner chunks of 128 floats
        __syncthreads();
#pragma unroll
        for (int it = 0; it < 4; ++it)
            *(float4*)&M[half*16 + lrow][(lc4 + 8*it)*4] = stg[it];
        if (half) {
#pragma unroll
            for (int it = 0; it < 4; ++it)
                rsq += stg[it].x*stg[it].x + stg[it].y*stg[it].y
                     + stg[it].z*stg[it].z + stg[it].w*stg[it].w;
        }
        __syncthreads();
        if (c + 1 < 8) {
#pragma unroll
            for (int it = 0; it < 4; ++it)
                stg[it] = *(const float4*)(gsrc + (size_t)(c+1)*128 + (lc4 + 8*it)*4);
        }
        float av[8][4], bv[8][4];
#pragma unroll
        for (int r = 0; r < 8; ++r)
            *(float4*)av[r] = *(const float4*)(Arow + r*132);
#pragma unroll
        for (int r = 0; r < 8; ++r)
            *(float4*)bv[r] = *(const float4*)(Brow + r*132);
#pragma unroll
        for (int dd = 0; dd < 4; ++dd)
#pragma unroll
            for (int i = 0; i < 8; ++i)
#pragma unroll
                for (int j = 0; j < 8; ++j)
                    acc[i][j] = fmaf(av[i][dd], bv[j][dd], acc[i][j]);
    }

    // reduce over the 8 d-slices within each wave
#pragma unroll
    for (int i = 0; i < 8; ++i)
#pragma unroll
        for (int j = 0; j < 8; ++j) {
            float v = acc[i][j];
            v += __shfl_xor(v, 8,  64);
            v += __shfl_xor(v, 16, 64);
            v += __shfl_xor(v, 32, 64);
            acc[i][j] = v;
        }

    rsq += __shfl_xor(rsq, 1, 64);
    rsq += __shfl_xor(rsq, 2, 64);
    rsq += __shfl_xor(rsq, 4, 64);
    if (half == 1 && (t & 7) == 0) rn2[lrow] = rsq;

    const int w = t >> 6;
    if ((t & 63) < 8) {                 // lanes 0..7 of each wave hold the tiles
#pragma unroll
        for (int i = 0; i < 8; ++i)
#pragma unroll
            for (int j = 0; j < 8; ++j)
                Gp[w][ti*8 + i][tj*8 + j] = acc[i][j];
    }
    __syncthreads();

    float* slotp = ws + (size_t)(b * 6 + slot) * 544;
    for (int e = t; e < 512; e += 256) {
        int n = e >> 5, m = e & 31;
        float v = Gp[0][n][m] + Gp[1][n][m] + Gp[2][n][m] + Gp[3][n][m];
        if (slot == 6) Gp[0][n][m] = v;
        else           slotp[e] = v;
    }
    if (slot != 6) {
        if (t < 16) slotp[512 + t] = rn2[t];
        return;                          // block-uniform exit
    }

    // ---- slot 6 (level 2): finish loss here ----
    __syncthreads();
    if (t < 16) {
        tnormS[t] = fmaxf(sqrtf(Gp[0][t][t]), NTX_EPS);
        rnormS[t] = fmaxf(sqrtf(rn2[t]), NTX_EPS);
    }
    __syncthreads();

    float loss = 0.f;
    if (t < 16) {
        const int n = t;
        const float itn = 2.0f / tnormS[n];
        float lg[32];
#pragma unroll
        for (int m = 0; m < 16; ++m)
            lg[m] = Gp[0][n][16 + m] * itn / rnormS[m];
#pragma unroll
        for (int k = 0; k < 16; ++k)
            lg[16 + k] = Gp[0][n][k] * itn / tnormS[k];
        const float pos = lg[n];
        float mx = -3.4e38f;
#pragma unroll
        for (int m = 0; m < 32; ++m)
            mx = (m == 16 + n) ? mx : fmaxf(mx, lg[m]);
        float sm = 0.f;
#pragma unroll
        for (int m = 0; m < 32; ++m)
            sm += (m == 16 + n) ? 0.f : expf(lg[m] - mx);
        loss = logf(sm) + mx - pos;
    }
    loss += __shfl_xor(loss, 1, 64);
    loss += __shfl_xor(loss, 2, 64);
    loss += __shfl_xor(loss, 4, 64);
    loss += __shfl_xor(loss, 8, 64);
    if (t == 0) atomicAdd(out, loss * (1.0f / 512.0f));
}

// Kernel 2: sum partial Grams for levels 0/1 and do the logsumexp.
// grid = B*2 (b = bid>>1, lvl = bid&1), block = 64.
__global__ __launch_bounds__(64)
void ntxent_finish(const float* __restrict__ ws, float* __restrict__ out)
{
    __shared__ float G[16][33];
    __shared__ float rn2s[16];
    __shared__ float tn[16], rn[16];

    const int bid = blockIdx.x;
    const int b   = bid >> 1;
    const int lvl = bid & 1;
    const int base = b * 6 + (lvl ? 4 : 0);
    const int cnt  = lvl ? 2 : 4;
    const int l = threadIdx.x;

    for (int e = l; e < 512; e += 64) {
        float s = 0.f;
        for (int c = 0; c < cnt; ++c) s += ws[(size_t)(base + c) * 544 + e];
        G[e >> 5][e & 31] = s;
    }
    if (l < 16) {
        float s = 0.f;
        for (int c = 0; c < cnt; ++c) s += ws[(size_t)(base + c) * 544 + 512 + l];
        rn2s[l] = s;
    }
    __syncthreads();
    if (l < 16) {
        tn[l] = fmaxf(sqrtf(G[l][l]), NTX_EPS);
        rn[l] = fmaxf(sqrtf(rn2s[l]), NTX_EPS);
    }
    __syncthreads();

    float loss = 0.f;
    if (l < 16) {
        const int n = l;
        const float itn = 2.0f / tn[n];
        float lg[32];
#pragma unroll
        for (int m = 0; m < 16; ++m)
            lg[m] = G[n][16 + m] * itn / rn[m];
#pragma unroll
        for (int k = 0; k < 16; ++k)
            lg[16 + k] = G[n][k] * itn / tn[k];
        const float pos = lg[n];
        float mx = -3.4e38f;
#pragma unroll
        for (int m = 0; m < 32; ++m)
            mx = (m == 16 + n) ? mx : fmaxf(mx, lg[m]);
        float sm = 0.f;
#pragma unroll
        for (int m = 0; m < 32; ++m)
            sm += (m == 16 + n) ? 0.f : expf(lg[m] - mx);
        loss = logf(sm) + mx - pos;
    }
    loss += __shfl_xor(loss, 1, 64);
    loss += __shfl_xor(loss, 2, 64);
    loss += __shfl_xor(loss, 4, 64);
    loss += __shfl_xor(loss, 8, 64);
    if (l == 0) atomicAdd(out, loss * (1.0f / 512.0f));
}

extern "C" void kernel_launch(void* const* d_in, const int* in_sizes, int n_in,
                              void* d_out, int out_size, void* d_ws, size_t ws_size,
                              hipStream_t stream) {
    const float* ts0 = (const float*)d_in[0];
    const float* rs0 = (const float*)d_in[1];
    const float* ts1 = (const float*)d_in[2];
    const float* rs1 = (const float*)d_in[3];
    const float* ts2 = (const float*)d_in[4];
    const float* rs2 = (const float*)d_in[5];
    float* out = (float*)d_out;
    float* ws  = (float*)d_ws;

    hipMemsetAsync(out, 0, sizeof(float), stream);

    const int B = in_sizes[0] / (16 * 4096);   // 256
    hipLaunchKernelGGL(ntxent_partial, dim3(B * 7), dim3(256), 0, stream,
                       ts0, rs0, ts1, rs1, ts2, rs2, ws, out);
    hipLaunchKernelGGL(ntxent_finish, dim3(B * 2), dim3(64), 0, stream,
                       ws, out);
}